// Round 9
// baseline (947.046 us; speedup 1.0000x reference)
//
#include <hip/hip_runtime.h>
#include <hip/hip_bf16.h>
#include <cstdint>

typedef __attribute__((ext_vector_type(8))) short short8;
typedef __attribute__((ext_vector_type(4))) float float4v;

#define LOG2E 1.44269504088896340736f
#define LN2   0.69314718055994530942f

#if __has_builtin(__builtin_amdgcn_exp2f)
__device__ __forceinline__ float fexp2(float x){ return __builtin_amdgcn_exp2f(x); }
#else
__device__ __forceinline__ float fexp2(float x){ return exp2f(x); }
#endif
#if __has_builtin(__builtin_amdgcn_logf)
__device__ __forceinline__ float flog2(float x){ return __builtin_amdgcn_logf(x); }
#else
__device__ __forceinline__ float flog2(float x){ return log2f(x); }
#endif

// hhat = log2(1 + 2^zhat); biases pre-scaled by log2e so GEMM on hhat yields
// the next zhat directly (ln2 * log2e == 1 cancels).
__device__ __forceinline__ float softplus_hat(float zh){
  return flog2(1.0f + fexp2(zh));
}

// softplus output > 0 -> truncation (RTZ) to bf16 is a 1-instr shift.
__device__ __forceinline__ unsigned short bf16_trunc(float f){
  return (unsigned short)(__builtin_bit_cast(unsigned int, f) >> 16);
}

// ---------------------------------------------------------------------------
// Pre-pass: Wh [S,4,256,256] fp32 -> bf16 slabs Wt[s*4+l][kb][n][ki]
// (kb = k/32, ki = k%32). B-frags read from GLOBAL: lanes {n,n+16,n+32,n+48}
// cover row n's 64B contiguously -> 1KB/wave-instr from L2.
// ---------------------------------------------------------------------------
__global__ void convert_wh(const float* __restrict__ Wh,
                           unsigned short* __restrict__ Wt){
  int e = blockIdx.x * 256 + threadIdx.x;          // 0 .. 2^21-1
  int n  = e & 255;
  int k  = (e >> 8) & 255;
  int sl = e >> 16;
  float v = Wh[e];
  __hip_bfloat16 h = __float2bfloat16(v);
  Wt[(sl << 16) + ((k >> 5) << 13) + (n << 5) + (k & 31)] =
      __builtin_bit_cast(unsigned short, h);
}

__device__ __forceinline__ float4v bf16_mfma(short8 a, short8 b, float4v c){
  return __builtin_amdgcn_mfma_f32_16x16x32_bf16(a, b, c, 0, 0, 0);
}

// ---------------------------------------------------------------------------
// h LDS layout: h[tile][octet o=k>>3][row m][j=k&7] bf16, 32KB/tile, no pad.
// A-read (row lane&15 + 16mi, octet 4kb+q): 16 lanes x contiguous 16B ->
// conflict-free; address = lane base + imm (kb*2048 + mi*128 elems).
// C-write: base (colb>>3)*512+(colb&7)+q*32, imm ni*1024+mi*128+r*8.
//
// Phase P (0..7): MFMA(tile P&1, layer P>>1) interleaved per-kb with
// softplus+store of the OTHER tile's acc (filled in phase P-1). Both tiles
// share the B stream: rotating 3-slot bq, stream pos x = 8P+kb, refill pos
// x+3 (layer (x+3)>>4) -> weights loaded ONCE per block, used by both tiles.
// ---------------------------------------------------------------------------
template<int P>
__device__ __forceinline__ void run_phase(
    const unsigned short* __restrict__ bbase0,
    const unsigned short* __restrict__ aS,     // self tile A-frag lane base
    unsigned short* __restrict__ cO,           // other tile C-store lane base
    short8 (&bq)[3][4],
    float4v (&accS)[4][4], float4v (&accO)[4][4],
    const float* __restrict__ bh_s, int colb,
    const float (&wv)[4], float (&pd)[16])
{
  constexpr int LYR = P >> 1;
  {
    float bias[4];
    #pragma unroll
    for (int ni = 0; ni < 4; ++ni)
      bias[ni] = bh_s[LYR * 256 + colb + ni * 16] * LOG2E;
    #pragma unroll
    for (int mi = 0; mi < 4; ++mi)
      #pragma unroll
      for (int ni = 0; ni < 4; ++ni)
        accS[mi][ni] = (float4v){bias[ni], bias[ni], bias[ni], bias[ni]};
  }

  short8 a0[4], a1[4];
  #pragma unroll
  for (int mi = 0; mi < 4; ++mi)
    a0[mi] = *(const short8*)(aS + mi * 128);

  #pragma unroll
  for (int kb = 0; kb < 8; ++kb) {
    short8* cur = (kb & 1) ? a1 : a0;
    short8* nxt = (kb & 1) ? a0 : a1;
    if (kb < 7) {                                  // A prefetch depth 1 (LDS)
      #pragma unroll
      for (int mi = 0; mi < 4; ++mi)
        nxt[mi] = *(const short8*)(aS + (kb + 1) * 2048 + mi * 128);
    }
    const int slot = (8 * P + kb) % 3;             // compile-time (unrolled)
    #pragma unroll
    for (int mi = 0; mi < 4; ++mi)
      #pragma unroll
      for (int ni = 0; ni < 4; ++ni)
        accS[mi][ni] = bf16_mfma(cur[mi], bq[slot][ni], accS[mi][ni]);

    // partner VALU chunk (2 of 16 acc groups per kb) -> in-wave MFMA overlap
    if constexpr (P >= 1 && P < 7) {
      #pragma unroll
      for (int g = 2 * kb; g < 2 * kb + 2; ++g) {
        const int mi = g >> 2, ni = g & 3;
        float4v v = accO[mi][ni];
        #pragma unroll
        for (int r = 0; r < 4; ++r)
          cO[ni * 1024 + mi * 128 + r * 8] = bf16_trunc(softplus_hat(v[r]));
      }
    } else if constexpr (P == 7) {                 // partner = A's layer3 -> dot
      #pragma unroll
      for (int g = 2 * kb; g < 2 * kb + 2; ++g) {
        const int mi = g >> 2, ni = g & 3;
        float4v v = accO[mi][ni];
        #pragma unroll
        for (int r = 0; r < 4; ++r)
          pd[mi * 4 + r] = fmaf(softplus_hat(v[r]), wv[ni], pd[mi * 4 + r]);
      }
    }

    const int x = 8 * P + kb + 3;                  // B refill, depth 3
    if (x <= 63) {
      const int XL = x >> 4, xkb = x & 7;
      #pragma unroll
      for (int ni = 0; ni < 4; ++ni)
        bq[slot][ni] = *(const short8*)(bbase0 + XL * 65536 + xkb * 8192 + ni * 512);
    }
  }
}

// ---------------------------------------------------------------------------
// Fused MLP, two-tile in-wave pipeline. Block = 2 x 64 rows x one series.
// Tiles: A = mblk, B = mblk + 1562 (grid 1563x8; tile 1562 duplicated with
// bit-identical writes -> benign). LDS exactly 64KB (2 x 32KB h).
// ---------------------------------------------------------------------------
__global__ __launch_bounds__(256, 2) void series_mlp(
    const float* __restrict__ coords,
    const float* __restrict__ W0, const float* __restrict__ b0,
    const float* __restrict__ bh,
    const float* __restrict__ Wout, const float* __restrict__ bout,
    const unsigned short* __restrict__ Wt,
    float* __restrict__ out)
{
  __shared__ __align__(16) unsigned short h[2][16384];   // 64 KB exactly

  const int tid  = threadIdx.x;
  const int lane = tid & 63;
  const int wn   = tid >> 6;
  const int s    = blockIdx.x & 7;           // series == XCD (round-robin)
  const int mblk = blockIdx.x >> 3;          // 0..1562
  const int m0A  = mblk * 64;
  const int m0B  = (mblk + 1562) * 64;       // covers tiles 1562..3124

  const int colb = (wn << 6) + (lane & 15);
  const int q    = lane >> 4;

  const unsigned short* bbase0 = Wt + ((s << 2) << 16) + (colb << 5) + (q << 3);

  short8 bq[3][4];                           // issue early: latency hides under layer0
  #pragma unroll
  for (int i = 0; i < 3; ++i)
    #pragma unroll
    for (int ni = 0; ni < 4; ++ni)
      bq[i][ni] = *(const short8*)(bbase0 + i * 8192 + ni * 512);

  // ---------------- layer 0 (K=3) for both tiles; coords wave-uniform -> SGPR --
  {
    const int c = tid;
    const float w0 = W0[(s * 3 + 0) * 256 + c] * LOG2E;
    const float w1 = W0[(s * 3 + 1) * 256 + c] * LOG2E;
    const float w2 = W0[(s * 3 + 2) * 256 + c] * LOG2E;
    const float bb = b0[s * 256 + c] * LOG2E;
    unsigned short* hA = &h[0][(c >> 3) * 512 + (c & 7)];
    unsigned short* hB = &h[1][(c >> 3) * 512 + (c & 7)];
    const float* cpA = coords + m0A * 3;
    const float* cpB = coords + m0B * 3;
    #pragma unroll 8
    for (int m = 0; m < 64; ++m) {
      float zA = fmaf(cpA[3*m+2], w2, fmaf(cpA[3*m+1], w1, fmaf(cpA[3*m], w0, bb)));
      float zB = fmaf(cpB[3*m+2], w2, fmaf(cpB[3*m+1], w1, fmaf(cpB[3*m], w0, bb)));
      hA[m * 8] = bf16_trunc(softplus_hat(zA));
      hB[m * 8] = bf16_trunc(softplus_hat(zB));
    }
  }
  __syncthreads();

  const unsigned short* aA = &h[0][q * 512 + (lane & 15) * 8];
  const unsigned short* aB = &h[1][q * 512 + (lane & 15) * 8];
  unsigned short* cA = &h[0][(colb >> 3) * 512 + (colb & 7) + q * 32];
  unsigned short* cB = &h[1][(colb >> 3) * 512 + (colb & 7) + q * 32];

  float wv[4];
  #pragma unroll
  for (int ni = 0; ni < 4; ++ni) wv[ni] = Wout[(s << 8) + colb + ni * 16];
  const float* bh_s = bh + (s << 10);

  float4v accA[4][4], accB[4][4];
  float pd[16];
  #pragma unroll
  for (int i = 0; i < 16; ++i) pd[i] = 0.f;

  run_phase<0>(bbase0, aA, cB, bq, accA, accB, bh_s, colb, wv, pd); __syncthreads();
  run_phase<1>(bbase0, aB, cA, bq, accB, accA, bh_s, colb, wv, pd); __syncthreads();
  run_phase<2>(bbase0, aA, cB, bq, accA, accB, bh_s, colb, wv, pd); __syncthreads();
  run_phase<3>(bbase0, aB, cA, bq, accB, accA, bh_s, colb, wv, pd); __syncthreads();
  run_phase<4>(bbase0, aA, cB, bq, accA, accB, bh_s, colb, wv, pd); __syncthreads();
  run_phase<5>(bbase0, aB, cA, bq, accB, accA, bh_s, colb, wv, pd); __syncthreads();
  run_phase<6>(bbase0, aA, cB, bq, accA, accB, bh_s, colb, wv, pd); __syncthreads();
  run_phase<7>(bbase0, aB, cA, bq, accB, accA, bh_s, colb, wv, pd);

  // pd = A's output partials. h[0] dead since phase 6 -> use as reduce scratch.
  float* redA = (float*)&h[0][0];                  // 64 rows x 68-stride floats
  #pragma unroll
  for (int mi = 0; mi < 4; ++mi)
    #pragma unroll
    for (int r = 0; r < 4; ++r)
      redA[(mi * 16 + q * 4 + r) * 68 + (wn << 4) + (lane & 15)] = pd[mi * 4 + r];
  __syncthreads();

  // tail: B's output dot (h[1] dead after phase 7's barrier above)
  float pd2[16];
  #pragma unroll
  for (int i = 0; i < 16; ++i) pd2[i] = 0.f;
  #pragma unroll
  for (int mi = 0; mi < 4; ++mi)
    #pragma unroll
    for (int ni = 0; ni < 4; ++ni) {
      float4v v = accB[mi][ni];
      #pragma unroll
      for (int r = 0; r < 4; ++r)
        pd2[mi * 4 + r] = fmaf(softplus_hat(v[r]), wv[ni], pd2[mi * 4 + r]);
    }
  float* redB = (float*)&h[1][0];
  #pragma unroll
  for (int mi = 0; mi < 4; ++mi)
    #pragma unroll
    for (int r = 0; r < 4; ++r)
      redB[(mi * 16 + q * 4 + r) * 68 + (wn << 4) + (lane & 15)] = pd2[mi * 4 + r];
  __syncthreads();

  if (tid < 128) {
    const int t = tid >> 6, r = tid & 63;
    const float* red = t ? (const float*)&h[1][0] : (const float*)&h[0][0];
    const float4v* rr = (const float4v*)&red[r * 68];
    float4v a = rr[0];
    #pragma unroll
    for (int i = 1; i < 16; ++i) {
      float4v b = rr[i];
      a.x += b.x; a.y += b.y; a.z += b.z; a.w += b.w;
    }
    float tot = (a.x + a.y) + (a.z + a.w);
    const int m0 = t ? m0B : m0A;
    out[(m0 + r) * 8 + s] = fmaf(LN2, tot, bout[s]);   // undo log2-domain
  }
}

// ---------------------------------------------------------------------------
// Fallback (scratch-free), fp32 VALU — only if ws_size < 4 MiB.
// ---------------------------------------------------------------------------
__global__ __launch_bounds__(256) void series_mlp_slow(
    const float* __restrict__ coords,
    const float* __restrict__ W0, const float* __restrict__ b0,
    const float* __restrict__ Wh, const float* __restrict__ bh,
    const float* __restrict__ Wout, const float* __restrict__ bout,
    float* __restrict__ out)
{
  __shared__ float hh[64 * 256];
  __shared__ float cbuf[192];
  __shared__ float red[256];
  const int tid = threadIdx.x;
  const int s   = blockIdx.y;
  const int m0  = blockIdx.x * 64;

  if (tid < 192) cbuf[tid] = coords[m0 * 3 + tid];
  __syncthreads();
  {
    const float w0 = W0[(s * 3 + 0) * 256 + tid];
    const float w1 = W0[(s * 3 + 1) * 256 + tid];
    const float w2 = W0[(s * 3 + 2) * 256 + tid];
    const float bb = b0[s * 256 + tid];
    for (int m = 0; m < 64; ++m) {
      float z = fmaf(cbuf[m * 3 + 2], w2,
                fmaf(cbuf[m * 3 + 1], w1,
                fmaf(cbuf[m * 3 + 0], w0, bb)));
      hh[m * 256 + tid] = LN2 * softplus_hat(z * LOG2E);
    }
  }
  __syncthreads();

  for (int l = 0; l < 4; ++l) {
    const float* W = Wh + (((s << 2) + l) << 16);
    const float bb = bh[((s << 2) + l) * 256 + tid];
    float acc[64];
    #pragma unroll
    for (int m = 0; m < 64; ++m) acc[m] = bb;
    for (int kc = 0; kc < 64; ++kc) {
      float w0 = W[(kc * 4 + 0) * 256 + tid];
      float w1 = W[(kc * 4 + 1) * 256 + tid];
      float w2 = W[(kc * 4 + 2) * 256 + tid];
      float w3 = W[(kc * 4 + 3) * 256 + tid];
      #pragma unroll
      for (int m = 0; m < 64; ++m) {
        float4v hv = *(const float4v*)&hh[m * 256 + kc * 4];
        acc[m] = fmaf(hv.w, w3, fmaf(hv.z, w2,
                 fmaf(hv.y, w1, fmaf(hv.x, w0, acc[m]))));
      }
    }
    __syncthreads();
    #pragma unroll
    for (int m = 0; m < 64; ++m)
      hh[m * 256 + tid] = LN2 * softplus_hat(acc[m] * LOG2E);
    __syncthreads();
  }
  {
    const int m = tid >> 2, qq = tid & 3;
    const float* wv = Wout + (s << 8);
    float sum = 0.f;
    for (int i = 0; i < 16; ++i) {
      int kk = (qq << 6) + ((((tid & 15) + i) << 2) & 63);
      float4v hv = *(const float4v*)&hh[m * 256 + kk];
      sum += hv.x * wv[kk] + hv.y * wv[kk + 1] + hv.z * wv[kk + 2] + hv.w * wv[kk + 3];
    }
    red[tid] = sum;
    __syncthreads();
    if (tid < 64)
      out[(m0 + tid) * 8 + s] =
          red[tid * 4] + red[tid * 4 + 1] + red[tid * 4 + 2] + red[tid * 4 + 3] + bout[s];
  }
}

extern "C" void kernel_launch(void* const* d_in, const int* in_sizes, int n_in,
                              void* d_out, int out_size, void* d_ws, size_t ws_size,
                              hipStream_t stream) {
  const float* coords = (const float*)d_in[0];
  const float* W0     = (const float*)d_in[1];
  const float* b0     = (const float*)d_in[2];
  const float* Wh     = (const float*)d_in[3];
  const float* bh     = (const float*)d_in[4];
  const float* Wout   = (const float*)d_in[5];
  const float* bout   = (const float*)d_in[6];
  float* out = (float*)d_out;

  const size_t WT_BYTES = (size_t)8 * 4 * 256 * 256 * 2;   // 4 MiB bf16 slabs
  if (ws_size >= WT_BYTES) {
    unsigned short* Wt = (unsigned short*)d_ws;
    convert_wh<<<8192, 256, 0, stream>>>(Wh, Wt);
    series_mlp<<<dim3(1563 * 8), dim3(256), 0, stream>>>(
        coords, W0, b0, bh, Wout, bout, Wt, out);
  } else {
    series_mlp_slow<<<dim3(3125, 8), dim3(256), 0, stream>>>(
        coords, W0, b0, Wh, bh, Wout, bout, out);
  }
  // second tuple output: echo coords
  hipMemcpyAsync(out + (size_t)200000 * 8, coords,
                 (size_t)200000 * 3 * sizeof(float),
                 hipMemcpyDeviceToDevice, stream);
}